// Round 7
// baseline (151.593 us; speedup 1.0000x reference)
//
#include <hip/hip_runtime.h>
#include <hip/hip_bf16.h>
#include <math.h>

typedef __hip_bfloat16 bf16;
typedef short bf16x8 __attribute__((ext_vector_type(8)));
typedef float f32x4 __attribute__((ext_vector_type(4)));
typedef unsigned short u16;

#define R_TOT 4096   // B*N
#define NJ 31

// ---- workspace layout (float element offsets) ----
#define OFF_AE   0          // ae as bf16 u16 (4096*256)
#define OFF_QK   1048576    // qk: 4096*10 floats
#define OFF_S1   2097152    // s1: 4096*256 floats
#define OFF_ENT  4542464    // 4096 floats
#define OFF_X    4546560    // x as bf16 u16 (4096*256)
#define OFF_W    5595136    // canonical weights base
#define OFF_G    6100992    // gumbel table: 4096*31*2 floats
// relative to W:
#define W_E1W   0
#define W_E1B   640
#define W_E2P   768        // e2 B-pack: 32768 bf16
#define W_E2B   33536
#define W_H1B   101120
#define W_VWP   101376     // vw B-pack: 8192 bf16
#define W_W1EP  167684     // W1e B-pack: 8192 bf16
#define W_HE2   171780     // E = he@hm2 PLAIN f32 [2][256]
#define W_CB    173828     // cb0, cb1
#define W_S1P   200452     // s1 B-pack: 65536 bf16
#define W_VW    235780
#define W_VB    238340
#define W_DECWT 238596     // dec B-pack: 262144 bf16
#define W_DECB  500740
#define W_QKM   501252     // M = qw^T@kw B-pack: 4096 bf16

// ---- output element offsets ----
#define OUT0 0
#define OUT1 2097152
#define OUT2 2224128
#define OUT3 2351104
#define OUT4 2351105
#define OUT5 2478081

__device__ __forceinline__ float b2f(bf16 x) { return __bfloat162float(x); }
__device__ __forceinline__ float ldin(const void* p, int i, int flag) {
    return flag ? b2f(((const bf16*)p)[i]) : ((const float*)p)[i];
}
__device__ __forceinline__ void stout(void* p, int i, float v, int flag) {
    if (flag) ((bf16*)p)[i] = __float2bfloat16(v);
    else      ((float*)p)[i] = v;
}
__device__ __forceinline__ u16 f2bbits(float v) {
    bf16 h = __float2bfloat16(v);
    return *(u16*)&h;
}
// per-wave inline dtype detect: P(misclassify) = 0.4^64 ~ 0
__device__ __forceinline__ int detect_flag(const void* emb) {
    float x = ((const float*)emb)[threadIdx.x & 63];
    int sane = (x == x) && (fabsf(x) < 1e20f);
    unsigned long long m = __ballot(sane);
    return (__popcll(m) == 64) ? 0 : 1;  // 0=fp32, 1=bf16
}

// ---------------- K0: prep what k_embed needs + gumbel table (783 blocks) ----------------
__global__ __launch_bounds__(256) void k_prep(
        const void* emb, const void* gum,
        const void* e1w, const void* e1b, const void* e2w, const void* e2b,
        const void* h1w, const void* h1b, const void* qw,  const void* kw,
        const void* vw,  const void* vb,  const void* decb,
        float* W, float* gws) {
    int flag = detect_flag(emb);
    int blk = blockIdx.x;
    int tid = threadIdx.x;
    if (blk < 384) {
        int p; const void* src; int ldm, Wdst;
        if (blk < 128) { p = blk * 256 + tid;         src = e2w; ldm = 128; Wdst = W_E2P; }
        else           { p = (blk - 128) * 256 + tid; src = h1w; ldm = 263; Wdst = W_S1P; }
        int jj   = p & 7;
        int lane = (p >> 3) & 63;
        int tile = p >> 9;
        int nt = tile & 15, kt = tile >> 4;
        int n = nt * 16 + (lane & 15);
        int k = kt * 32 + ((lane >> 4) << 3) + jj;
        ((u16*)(W + Wdst))[p] = f2bbits(ldin(src, n * ldm + k, flag));
    } else if (blk < 640) {
        // qkm: M[c][n] = sum_d qw[d*256+c]*kw[d*10+n]; 16 lanes per entry
        int p = (blk - 384) * 16 + (tid >> 4);
        int l = tid & 15;
        int jj = p & 7, lane = (p >> 3) & 63, kt = p >> 9;
        int k = kt * 32 + ((lane >> 4) << 3) + jj;
        int n = lane & 15;
        float v = 0.f;
        if (n < 10) {
#pragma unroll
            for (int dd = 0; dd < 16; dd++) {
                int d = l + 16 * dd;
                v += ldin(qw, d * 256 + k, flag) * ldin(kw, d * 10 + n, flag);
            }
        }
        v += __shfl_xor(v, 1, 64); v += __shfl_xor(v, 2, 64);
        v += __shfl_xor(v, 4, 64); v += __shfl_xor(v, 8, 64);
        if (l == 0) ((u16*)(W + W_QKM))[p] = f2bbits(v);
    } else if (blk < 659) {
        int q2 = (blk - 640) * 256 + tid;
        if      (q2 < 640)   W[W_E1W  + q2]           = ldin(e1w,  q2,          flag);
        else if (q2 < 768)   W[W_E1B  + (q2 - 640)]   = ldin(e1b,  q2 - 640,    flag);
        else if (q2 < 1024)  W[W_E2B  + (q2 - 768)]   = ldin(e2b,  q2 - 768,    flag);
        else if (q2 < 1280)  W[W_H1B  + (q2 - 1024)]  = ldin(h1b,  q2 - 1024,   flag);
        else if (q2 < 3840)  W[W_VW   + (q2 - 1280)]  = ldin(vw,   q2 - 1280,   flag);
        else if (q2 < 4096)  W[W_VB   + (q2 - 3840)]  = ldin(vb,   q2 - 3840,   flag);
        else if (q2 < 4608)  W[W_DECB + (q2 - 4096)]  = ldin(decb, q2 - 4096,   flag);
    } else {
        // gumbel table: g = -log(-log(u+1e-10)+1e-10); 253952 elems, 8/thread, 124 blocks
        int t = (blk - 659) * 256 + tid;
#pragma unroll
        for (int j = 0; j < 8; j++) {
            int e = t * 8 + j;
            float u = ldin(gum, e, flag);
            gws[e] = -logf(-logf(u + 1e-10f) + 1e-10f);
        }
    }
}

// ---------------- K1: embed MLP + s1 + qk via MFMA (blocks 0..255)
//                    + concurrent packing for later kernels (blocks 256..424) ----------------
__global__ __launch_bounds__(256) void k_embed(const void* emb, const float* W_,
                                               const void* h1w, const void* h2w, const void* h2b,
                                               const void* hew, const void* heb, const void* decw,
                                               const void* vw,
                                               u16* aeb, float* qkws, float* s1ws) {
    int flag = detect_flag(emb);
    float* W = (float*)W_;
    int blk = blockIdx.x;
    int tid = threadIdx.x;
    if (blk >= 256) {
        if (blk < 384) {
            // DECWT pack, vectorized 8/thread
            int t = (blk - 256) * 256 + tid;
            int lane = t & 63, tile = t >> 6;
            int nt = tile & 31, kt = tile >> 5;
            int n = nt * 16 + (lane & 15);
            int k0 = kt * 32 + ((lane >> 4) << 3);
            u16 tmp[8];
#pragma unroll
            for (int j = 0; j < 8; j++) tmp[j] = f2bbits(ldin(decw, n * 512 + k0 + j, flag));
            *reinterpret_cast<int4*>((u16*)(W + W_DECWT) + t * 8) = *reinterpret_cast<int4*>(tmp);
        } else if (blk < 388) {
            // W1EP pack (edge cols 256..262 of h1w, pad to 8), vectorized
            int t = (blk - 384) * 256 + tid;   // < 1024
            int lane = t & 63, nt = t >> 6;
            int n = nt * 16 + (lane & 15);
            int k0 = (lane >> 4) << 3;
            u16 tmp[8];
#pragma unroll
            for (int j = 0; j < 8; j++) {
                int k = k0 + j;
                tmp[j] = (k < 7) ? f2bbits(ldin(h1w, n * 263 + 256 + k, flag)) : (u16)0;
            }
            *reinterpret_cast<int4*>((u16*)(W + W_W1EP) + t * 8) = *reinterpret_cast<int4*>(tmp);
        } else if (blk < 392) {
            // VWP pack (K=10 real, pad to 32), vectorized
            int t = (blk - 388) * 256 + tid;   // < 1024
            int lane = t & 63, nt = t >> 6;
            int n = nt * 16 + (lane & 15);
            int k0 = (lane >> 4) << 3;
            u16 tmp[8];
#pragma unroll
            for (int j = 0; j < 8; j++) {
                int k = k0 + j;
                tmp[j] = (k < 10) ? f2bbits(ldin(vw, n * 10 + k, flag)) : (u16)0;
            }
            *reinterpret_cast<int4*>((u16*)(W + W_VWP) + t * 8) = *reinterpret_cast<int4*>(tmp);
        } else if (blk < 424) {
            // E plain f32: E[n][c] = sum_d hew[n][d]*h2w[d][c]; 512 entries, 16 lanes each
            int e = (blk - 392) * 16 + (tid >> 4);   // < 512
            int l = tid & 15;
            int n = e >> 8, c = e & 255;
            float v = 0.f;
#pragma unroll
            for (int dd = 0; dd < 16; dd++) {
                int d = l + 16 * dd;
                v += ldin(hew, n * 256 + d, flag) * ldin(h2w, d * 256 + c, flag);
            }
            v += __shfl_xor(v, 1, 64); v += __shfl_xor(v, 2, 64);
            v += __shfl_xor(v, 4, 64); v += __shfl_xor(v, 8, 64);
            if (l == 0) W[W_HE2 + e] = v;
        } else {
            // CB: cb[i] = (he_row_i . h2b) + heb[i]
            if (tid < 32) {
                int i = tid >> 4, l = tid & 15;
                float v = 0.f;
#pragma unroll
                for (int dd = 0; dd < 16; dd++) {
                    int d = l + 16 * dd;
                    v += ldin(hew, i * 256 + d, flag) * ldin(h2b, d, flag);
                }
                v += __shfl_xor(v, 1, 64); v += __shfl_xor(v, 2, 64);
                v += __shfl_xor(v, 4, 64); v += __shfl_xor(v, 8, 64);
                if (l == 0) W[W_CB + i] = v + ldin(heb, i, flag);
            }
        }
        return;
    }
    // ---- embed path (blocks 0..255, 16 rows each) ----
    int r0 = blk * 16;
    __shared__ float embL[16][12];
    __shared__ u16 hB[16][136];
    __shared__ u16 aeB[16][264];
    for (int idx = tid; idx < 16 * 11; idx += 256) {
        int s = idx / 11, t = idx % 11;
        embL[s][t] = ldin(emb, (r0 + s) * 11 + t, flag);
    }
    __syncthreads();
    for (int idx = tid; idx < 16 * 128; idx += 256) {
        int s = idx >> 7, jo = idx & 127;
        float v = W[W_E1B + jo];
#pragma unroll
        for (int t = 0; t < 5; t++) v += W[W_E1W + jo * 5 + t] * embL[s][4 + t];
        hB[s][jo] = f2bbits(v > 0.f ? v : 0.01f * v);
    }
    __syncthreads();
    int wv = tid >> 6, ln = tid & 63;
    int lr = ln & 15, quad = ln >> 4;
    {
        const bf16x8* Bp = (const bf16x8*)(W + W_E2P);
        f32x4 acc[4];
#pragma unroll
        for (int nt = 0; nt < 4; nt++) acc[nt] = (f32x4){0.f, 0.f, 0.f, 0.f};
#pragma unroll
        for (int kt = 0; kt < 4; kt++) {
            bf16x8 af = *(const bf16x8*)&hB[lr][kt * 32 + (quad << 3)];
#pragma unroll
            for (int nt = 0; nt < 4; nt++) {
                bf16x8 bfr = Bp[(kt * 16 + (wv * 4 + nt)) * 64 + ln];
                acc[nt] = __builtin_amdgcn_mfma_f32_16x16x32_bf16(af, bfr, acc[nt], 0, 0, 0);
            }
        }
#pragma unroll
        for (int nt = 0; nt < 4; nt++) {
            int d = wv * 64 + nt * 16 + lr;
            float bias = W[W_E2B + d];
#pragma unroll
            for (int reg = 0; reg < 4; reg++) {
                int m = quad * 4 + reg;
                float v = acc[nt][reg] + bias;
                v = v > 0.f ? v : 0.01f * v;
                u16 bits = f2bbits(v);
                aeB[m][d] = bits;
                aeb[(r0 + m) * 256 + d] = bits;
            }
        }
    }
    __syncthreads();
    {
        const bf16x8* Bs = (const bf16x8*)(W + W_S1P);
        f32x4 sac[4];
#pragma unroll
        for (int nt = 0; nt < 4; nt++) sac[nt] = (f32x4){0.f, 0.f, 0.f, 0.f};
#pragma unroll
        for (int kt = 0; kt < 8; kt++) {
            bf16x8 af = *(const bf16x8*)&aeB[lr][kt * 32 + (quad << 3)];
#pragma unroll
            for (int nt = 0; nt < 4; nt++) {
                bf16x8 bs = Bs[(kt * 16 + (wv * 4 + nt)) * 64 + ln];
                sac[nt] = __builtin_amdgcn_mfma_f32_16x16x32_bf16(af, bs, sac[nt], 0, 0, 0);
            }
        }
#pragma unroll
        for (int nt = 0; nt < 4; nt++) {
            int d = wv * 64 + nt * 16 + lr;
            float bias = W[W_H1B + d];
#pragma unroll
            for (int reg = 0; reg < 4; reg++) {
                int m = quad * 4 + reg;
                s1ws[(r0 + m) * 256 + d] = sac[nt][reg] + bias;
            }
        }
        if (wv == 0) {
            const bf16x8* Bm = (const bf16x8*)(W + W_QKM);
            f32x4 qk = (f32x4){0.f, 0.f, 0.f, 0.f};
#pragma unroll
            for (int kt = 0; kt < 8; kt++) {
                bf16x8 af = *(const bf16x8*)&aeB[lr][kt * 32 + (quad << 3)];
                qk = __builtin_amdgcn_mfma_f32_16x16x32_bf16(af, Bm[kt * 64 + ln], qk, 0, 0, 0);
            }
            if (lr < 10) {
#pragma unroll
                for (int reg = 0; reg < 4; reg++) {
                    int m = quad * 4 + reg;
                    qkws[(r0 + m) * 10 + lr] = qk[reg];
                }
            }
        }
    }
}

// ---------------- K2: fused edges + hard MLP (logits in-register) + gumbel + attention + V + entropy ----------------
// Latency-bound: prefetch all exposed global scalars at head; logits folded into
// stage A epilogue (16 FMA + shuffle-tree) -> no a1 LDS, no stage-B MFMA, one fewer barrier.
__global__ __launch_bounds__(256) void k_fused(const void* emb, const float* gws,
                                               const float* s1ws, const float* qkws, const float* W,
                                               u16* xb, float* entws, void* out) {
    int flag = detect_flag(emb);
    int r = blockIdx.x;
    int b = r >> 5, i = r & 31;
    __shared__ float embB[32][12];
    __shared__ float seL[32][10];
    __shared__ u16 eA[32][40];      // 10 real features; rows 80 B (16B-aligned, 20-bank stride)
    __shared__ float pj[4][32][2];
    __shared__ float cL[32];
    __shared__ float qkL[10];
    int tid = threadIdx.x;
    int wv = tid >> 6, ln = tid & 63;
    int lr = ln & 15, quad = ln >> 4;
    // ---- early prefetch (hides ~500-900cy global latency under embB+edge phase) ----
    float s1pre[4], vbpre[4], e0pre[4], e1pre[4];
#pragma unroll
    for (int nt = 0; nt < 4; nt++) {
        int d = (wv * 4 + nt) * 16 + lr;
        s1pre[nt] = s1ws[r * 256 + d];
        vbpre[nt] = W[W_VB + d];
        e0pre[nt] = W[W_HE2 + d];
        e1pre[nt] = W[W_HE2 + 256 + d];
    }
    float2 g01 = make_float2(0.f, 0.f);
    if (wv == 0 && ln < NJ)
        g01 = *reinterpret_cast<const float2*>(&gws[(r * NJ + ln) * 2]);
    for (int idx = tid; idx < 32 * 11; idx += 256) {
        int s = idx / 11, t = idx % 11;
        embB[s][t] = ldin(emb, (b * 32 + s) * 11 + t, flag);
    }
    for (int idx = tid; idx < 32 * 40; idx += 256) ((u16*)eA)[idx] = 0;
    if (tid >= 64 && tid < 74) qkL[tid - 64] = qkws[r * 10 + (tid - 64)];
    __syncthreads();
    // edge features via algebraic identities (no atan2/sincos)
    if (tid < NJ) {
        int jp = tid;
        int j = jp + (jp >= i ? 1 : 0);
        float pix = embB[i][0], piy = embB[i][1], hix = embB[i][2], hiy = embB[i][3];
        float pjx = embB[j][0], pjy = embB[j][1], hjx = embB[j][2], hjy = embB[j][3];
        float ajx = embB[j][7], ajy = embB[j][8];
        float gjx = embB[j][9], gjy = embB[j][10];
        float hn2 = hix * hix + hiy * hiy;
        float csh, snh;
        if (hn2 == 0.f) { csh = 1.f; snh = 0.f; }
        else { float invh = rsqrtf(hn2); csh = hix * invh; snh = hiy * invh; }
        float dx = pjx - pix, dy = pjy - piy;
        float d2 = dx * dx + dy * dy;
        float dist, csd, snd;
        if (d2 == 0.f) { dist = 0.f; csd = 1.f; snd = 0.f; }
        else { float invd = rsqrtf(d2); dist = d2 * invd; csd = dx * invd; snd = dy * invd; }
        float gx = gjx - pix, gy = gjy - piy;
        float g2 = gx * gx + gy * gy;
        float gdist, csg, sng;
        if (g2 == 0.f) { gdist = 0.f; csg = 1.f; sng = 0.f; }
        else { float invg = rsqrtf(g2); gdist = g2 * invg; csg = gx * invg; sng = gy * invg; }
        float f[10];
        f[0] = dist * (1.f / 12.f);
        f[1] = csd * csh + snd * snh;      // cos(theta_d - theta_h)
        f[2] = snd * csh - csd * snh;      // sin(theta_d - theta_h)
        f[3] = hjx; f[4] = hjy; f[5] = ajx; f[6] = ajy;
        f[7] = gdist;
        f[8] = csg * csh + sng * snh;
        f[9] = sng * csh - csg * snh;
#pragma unroll
        for (int t = 0; t < 10; t++) { seL[jp][t] = f[t]; eA[jp][t] = f2bbits(f[t]); }
        stout(out, OUT2 + r * NJ + jp, dist, flag);
    }
    __syncthreads();
    // A-fragments shared by stage A (W1e: zeros for k>=7) and stage V (vw: zeros for k>=10)
    bf16x8 af0 = *(const bf16x8*)&eA[lr][quad << 3];
    bf16x8 af1 = *(const bf16x8*)&eA[16 + lr][quad << 3];
    f32x4 vacc[2][4];
    float pl0[2][4], pl1[2][4];
#pragma unroll
    for (int mt = 0; mt < 2; mt++)
#pragma unroll
        for (int reg = 0; reg < 4; reg++) { pl0[mt][reg] = 0.f; pl1[mt][reg] = 0.f; }
    {
        const bf16x8* Bp = (const bf16x8*)(W + W_W1EP);
        const bf16x8* Bv = (const bf16x8*)(W + W_VWP);
#pragma unroll
        for (int nt = 0; nt < 4; nt++) {
            int gnt = wv * 4 + nt;
            float s1v = s1pre[nt];
            f32x4 acc0 = (f32x4){s1v, s1v, s1v, s1v};
            f32x4 acc1 = acc0;
            bf16x8 bb = Bp[gnt * 64 + ln];
            acc0 = __builtin_amdgcn_mfma_f32_16x16x32_bf16(af0, bb, acc0, 0, 0, 0);
            acc1 = __builtin_amdgcn_mfma_f32_16x16x32_bf16(af1, bb, acc1, 0, 0, 0);
            float e0 = e0pre[nt], e1 = e1pre[nt];
#pragma unroll
            for (int reg = 0; reg < 4; reg++) {
                float r0v = fmaxf(acc0[reg], 0.f);
                float r1v = fmaxf(acc1[reg], 0.f);
                pl0[0][reg] += r0v * e0;  pl1[0][reg] += r0v * e1;
                pl0[1][reg] += r1v * e0;  pl1[1][reg] += r1v * e1;
            }
            // V = edge @ vw^T (bias applied in epilogue)
            bf16x8 bv = Bv[gnt * 64 + ln];
            f32x4 z = (f32x4){0.f, 0.f, 0.f, 0.f};
            vacc[0][nt] = __builtin_amdgcn_mfma_f32_16x16x32_bf16(af0, bv, z, 0, 0, 0);
            vacc[1][nt] = __builtin_amdgcn_mfma_f32_16x16x32_bf16(af1, bv, z, 0, 0, 0);
        }
    }
    // reduce logit partials over the 16 lanes (lr) of each quad-group
#pragma unroll
    for (int s = 1; s <= 8; s <<= 1) {
#pragma unroll
        for (int mt = 0; mt < 2; mt++)
#pragma unroll
            for (int reg = 0; reg < 4; reg++) {
                pl0[mt][reg] += __shfl_xor(pl0[mt][reg], s, 64);
                pl1[mt][reg] += __shfl_xor(pl1[mt][reg], s, 64);
            }
    }
    if (lr == 0) {
#pragma unroll
        for (int mt = 0; mt < 2; mt++)
#pragma unroll
            for (int reg = 0; reg < 4; reg++) {
                int j = mt * 16 + (quad << 2) + reg;
                pj[wv][j][0] = pl0[mt][reg];
                pj[wv][j][1] = pl1[mt][reg];
            }
    }
    __syncthreads();
    // stage C (wave 0): gumbel + softmax + combined + entropy
    if (wv == 0) {
        if (ln == 31) cL[31] = 0.f;   // padded j-row for V epilogue
        float hwv = 0.f;
        if (ln < NJ) {
            float p0 = pj[0][ln][0] + pj[1][ln][0] + pj[2][ln][0] + pj[3][ln][0];
            float p1 = pj[0][ln][1] + pj[1][ln][1] + pj[2][ln][1] + pj[3][ln][1];
            float l0 = p0 + W[W_CB + 0], l1 = p1 + W[W_CB + 1];
            float dl = ((l1 + g01.y) - (l0 + g01.x)) * 2.0f;  // / tau (=0.5)
            hwv = 1.f / (1.f + __expf(-dl));
            stout(out, OUT1 + r * NJ + ln, l1, flag);
            stout(out, OUT4 + r * NJ + ln, hwv, flag);
        }
        float sc = -1e30f;
        if (ln < NJ) {
            float p = 0.f;
#pragma unroll
            for (int t = 0; t < 10; t++) p += qkL[t] * seL[ln][t];
            sc = p * (1.f / 16.f);
        }
        float m = sc;
#pragma unroll
        for (int s = 32; s >= 1; s >>= 1) m = fmaxf(m, __shfl_xor(m, s, 64));
        float e = (ln < NJ) ? __expf(sc - m) : 0.f;
        float sum = e;
#pragma unroll
        for (int s = 32; s >= 1; s >>= 1) sum += __shfl_xor(sum, s, 64);
        float sw = e / sum;
        float cmb = sw * hwv;
        if (ln < NJ) {
            cL[ln] = cmb;
            stout(out, OUT5 + r * NJ + ln, cmb, flag);
        }
        float csum = cmb;
#pragma unroll
        for (int s = 32; s >= 1; s >>= 1) csum += __shfl_xor(csum, s, 64);
        float cwn = cmb / (csum + 1e-6f);
        float et = (ln < NJ) ? -cwn * __logf(cwn + 1e-6f) : 0.f;
#pragma unroll
        for (int s = 32; s >= 1; s >>= 1) et += __shfl_xor(et, s, 64);
        if (ln == 0) entws[r] = et;
    }
    __syncthreads();
    // stage D: x[d] = sum_j relu(V[j][d] + vb[d]) * combined_j  (from V-MFMA accumulators)
    {
        float cj[2][4];
#pragma unroll
        for (int mt = 0; mt < 2; mt++)
#pragma unroll
            for (int reg = 0; reg < 4; reg++) cj[mt][reg] = cL[mt * 16 + (quad << 2) + reg];
#pragma unroll
        for (int nt = 0; nt < 4; nt++) {
            int d = (wv * 4 + nt) * 16 + lr;
            float xp = 0.f;
#pragma unroll
            for (int mt = 0; mt < 2; mt++)
#pragma unroll
                for (int reg = 0; reg < 4; reg++)
                    xp += fmaxf(vacc[mt][nt][reg] + vbpre[nt], 0.f) * cj[mt][reg];
            xp += __shfl_xor(xp, 16, 64);
            xp += __shfl_xor(xp, 32, 64);
            if (quad == 0) xb[r * 256 + d] = f2bbits(xp);
        }
    }
}

// ---------------- K3: decoder via MFMA (16-row blocks, 1024 blocks) + entropy epilogue ----------------
__global__ __launch_bounds__(256) void k_dec(const void* emb, const u16* aeb, const u16* xb,
                                             const float* W, const float* entws, void* out) {
    int flag = detect_flag(emb);
    int r0 = (blockIdx.x >> 2) * 16;
    int nq = blockIdx.x & 3;
    __shared__ u16 finB[16][520];
    int tid = threadIdx.x;
    for (int idx = tid; idx < 16 * 64; idx += 256) {
        int s = idx >> 6, c8 = idx & 63;
        int4 v;
        if (c8 < 32) v = *reinterpret_cast<const int4*>(aeb + (r0 + s) * 256 + c8 * 8);
        else         v = *reinterpret_cast<const int4*>(xb  + (r0 + s) * 256 + (c8 - 32) * 8);
        *reinterpret_cast<int4*>(&finB[s][c8 * 8]) = v;
    }
    __syncthreads();
    int wv = tid >> 6, ln = tid & 63;
    int lr = ln & 15, quad = ln >> 4;
    const bf16x8* Bp = (const bf16x8*)(W + W_DECWT);
    f32x4 acc[2];
    acc[0] = (f32x4){0.f, 0.f, 0.f, 0.f};
    acc[1] = (f32x4){0.f, 0.f, 0.f, 0.f};
#pragma unroll
    for (int kt = 0; kt < 16; kt++) {
        bf16x8 af = *(const bf16x8*)&finB[lr][kt * 32 + (quad << 3)];
#pragma unroll
        for (int nt = 0; nt < 2; nt++) {
            int gnt = nq * 8 + wv * 2 + nt;
            bf16x8 bfr = Bp[(kt * 32 + gnt) * 64 + ln];
            acc[nt] = __builtin_amdgcn_mfma_f32_16x16x32_bf16(af, bfr, acc[nt], 0, 0, 0);
        }
    }
#pragma unroll
    for (int nt = 0; nt < 2; nt++) {
        int d = (nq * 8 + wv * 2 + nt) * 16 + lr;
        float bias = W[W_DECB + d];
#pragma unroll
        for (int reg = 0; reg < 4; reg++) {
            int m = quad * 4 + reg;
            stout(out, OUT0 + (r0 + m) * 512 + d, acc[nt][reg] + bias, flag);
        }
    }
    // entropy mean epilogue on block 0 (entws is complete before this kernel starts)
    if (blockIdx.x == 0) {
        __shared__ float red[4];
        float s = 0.f;
        for (int i2 = tid; i2 < R_TOT; i2 += 256) s += entws[i2];
#pragma unroll
        for (int m = 32; m >= 1; m >>= 1) s += __shfl_xor(s, m, 64);
        if ((tid & 63) == 0) red[tid >> 6] = s;
        __syncthreads();
        if (tid == 0) {
            float t = red[0] + red[1] + red[2] + red[3];
            stout(out, OUT3, t / (float)R_TOT, flag);
        }
    }
}

// ---------------- launch ----------------
extern "C" void kernel_launch(void* const* d_in, const int* in_sizes, int n_in,
                              void* d_out, int out_size, void* d_ws, size_t ws_size,
                              hipStream_t stream) {
    const void* emb  = d_in[0];
    const void* gum  = d_in[1];
    const void* e1w  = d_in[2];
    const void* e1b  = d_in[3];
    const void* e2w  = d_in[4];
    const void* e2b  = d_in[5];
    const void* h1w  = d_in[6];
    const void* h1b  = d_in[7];
    const void* h2w  = d_in[8];
    const void* h2b  = d_in[9];
    const void* hew  = d_in[10];
    const void* heb  = d_in[11];
    const void* qw   = d_in[12];
    const void* kw   = d_in[13];
    const void* vw   = d_in[14];
    const void* vb   = d_in[15];
    const void* decw = d_in[16];
    const void* decb = d_in[17];

    float* wsf = (float*)d_ws;
    u16*   aeb  = (u16*)(wsf + OFF_AE);
    float* qkws = wsf + OFF_QK;
    float* s1ws = wsf + OFF_S1;
    float* entw = wsf + OFF_ENT;
    u16*   xb   = (u16*)(wsf + OFF_X);
    float* W    = wsf + OFF_W;
    float* gws  = wsf + OFF_G;

    hipLaunchKernelGGL(k_prep, dim3(783), dim3(256), 0, stream,
                       emb, gum, e1w, e1b, e2w, e2b, h1w, h1b, qw, kw, vw, vb, decb, W, gws);
    hipLaunchKernelGGL(k_embed, dim3(425), dim3(256), 0, stream,
                       emb, W, h1w, h2w, h2b, hew, heb, decw, vw, aeb, qkws, s1ws);
    hipLaunchKernelGGL(k_fused, dim3(4096), dim3(256), 0, stream,
                       emb, gws, s1ws, qkws, W, xb, entw, d_out);
    hipLaunchKernelGGL(k_dec, dim3(1024), dim3(256), 0, stream, emb, aeb, xb, W, entw, d_out);
}

// Round 8
// 145.111 us; speedup vs baseline: 1.0447x; 1.0447x over previous
//
#include <hip/hip_runtime.h>
#include <hip/hip_bf16.h>
#include <math.h>

typedef __hip_bfloat16 bf16;
typedef short bf16x8 __attribute__((ext_vector_type(8)));
typedef float f32x4 __attribute__((ext_vector_type(4)));
typedef unsigned short u16;

#define R_TOT 4096   // B*N
#define NJ 31

// ---- workspace layout (float element offsets) ----
#define OFF_AE   0          // ae as bf16 u16 (4096*256)
#define OFF_QK   1048576    // qk: 4096*10 floats
#define OFF_S1   2097152    // s1: 4096*256 floats
#define OFF_ENT  4542464    // 4096 floats
#define OFF_X    4546560    // x as bf16 u16 (4096*256)
#define OFF_W    5595136    // canonical weights base
#define OFF_G    6100992    // gumbel table: 4096*31*2 floats
// relative to W:
#define W_E1W   0
#define W_E1B   640
#define W_E2P   768        // e2 B-pack: 32768 bf16
#define W_E2B   33536
#define W_H1B   101120
#define W_VWP   101376     // vw B-pack: 8192 bf16
#define W_W1EP  167684     // W1e B-pack: 8192 bf16
#define W_HE2P  171780     // E = he@hm2 B-pack: 4096 bf16
#define W_CB    173828     // cb0, cb1
#define W_S1P   200452     // s1 B-pack: 65536 bf16
#define W_VW    235780
#define W_VB    238340
#define W_DECWT 238596     // dec B-pack: 262144 bf16
#define W_DECB  500740
#define W_QKM   501252     // M = qw^T@kw B-pack: 4096 bf16

// ---- output element offsets ----
#define OUT0 0
#define OUT1 2097152
#define OUT2 2224128
#define OUT3 2351104
#define OUT4 2351105
#define OUT5 2478081

__device__ __forceinline__ float b2f(bf16 x) { return __bfloat162float(x); }
__device__ __forceinline__ float ldin(const void* p, int i, int flag) {
    return flag ? b2f(((const bf16*)p)[i]) : ((const float*)p)[i];
}
__device__ __forceinline__ void stout(void* p, int i, float v, int flag) {
    if (flag) ((bf16*)p)[i] = __float2bfloat16(v);
    else      ((float*)p)[i] = v;
}
__device__ __forceinline__ u16 f2bbits(float v) {
    bf16 h = __float2bfloat16(v);
    return *(u16*)&h;
}
// per-wave inline dtype detect: P(misclassify) = 0.4^64 ~ 0
__device__ __forceinline__ int detect_flag(const void* emb) {
    float x = ((const float*)emb)[threadIdx.x & 63];
    int sane = (x == x) && (fabsf(x) < 1e20f);
    unsigned long long m = __ballot(sane);
    return (__popcll(m) == 64) ? 0 : 1;  // 0=fp32, 1=bf16
}

// ---------------- K0: prep what k_embed needs + gumbel table (783 blocks) ----------------
__global__ __launch_bounds__(256) void k_prep(
        const void* emb, const void* gum,
        const void* e1w, const void* e1b, const void* e2w, const void* e2b,
        const void* h1w, const void* h1b, const void* qw,  const void* kw,
        const void* vw,  const void* vb,  const void* decb,
        float* W, float* gws) {
    int flag = detect_flag(emb);
    int blk = blockIdx.x;
    int tid = threadIdx.x;
    if (blk < 384) {
        int p; const void* src; int ldm, Wdst;
        if (blk < 128) { p = blk * 256 + tid;         src = e2w; ldm = 128; Wdst = W_E2P; }
        else           { p = (blk - 128) * 256 + tid; src = h1w; ldm = 263; Wdst = W_S1P; }
        int jj   = p & 7;
        int lane = (p >> 3) & 63;
        int tile = p >> 9;
        int nt = tile & 15, kt = tile >> 4;
        int n = nt * 16 + (lane & 15);
        int k = kt * 32 + ((lane >> 4) << 3) + jj;
        ((u16*)(W + Wdst))[p] = f2bbits(ldin(src, n * ldm + k, flag));
    } else if (blk < 640) {
        // qkm: M[c][n] = sum_d qw[d*256+c]*kw[d*10+n]; 16 lanes per entry
        int p = (blk - 384) * 16 + (tid >> 4);
        int l = tid & 15;
        int jj = p & 7, lane = (p >> 3) & 63, kt = p >> 9;
        int k = kt * 32 + ((lane >> 4) << 3) + jj;
        int n = lane & 15;
        float v = 0.f;
        if (n < 10) {
#pragma unroll
            for (int dd = 0; dd < 16; dd++) {
                int d = l + 16 * dd;
                v += ldin(qw, d * 256 + k, flag) * ldin(kw, d * 10 + n, flag);
            }
        }
        v += __shfl_xor(v, 1, 64); v += __shfl_xor(v, 2, 64);
        v += __shfl_xor(v, 4, 64); v += __shfl_xor(v, 8, 64);
        if (l == 0) ((u16*)(W + W_QKM))[p] = f2bbits(v);
    } else if (blk < 659) {
        int q2 = (blk - 640) * 256 + tid;
        if      (q2 < 640)   W[W_E1W  + q2]           = ldin(e1w,  q2,          flag);
        else if (q2 < 768)   W[W_E1B  + (q2 - 640)]   = ldin(e1b,  q2 - 640,    flag);
        else if (q2 < 1024)  W[W_E2B  + (q2 - 768)]   = ldin(e2b,  q2 - 768,    flag);
        else if (q2 < 1280)  W[W_H1B  + (q2 - 1024)]  = ldin(h1b,  q2 - 1024,   flag);
        else if (q2 < 3840)  W[W_VW   + (q2 - 1280)]  = ldin(vw,   q2 - 1280,   flag);
        else if (q2 < 4096)  W[W_VB   + (q2 - 3840)]  = ldin(vb,   q2 - 3840,   flag);
        else if (q2 < 4608)  W[W_DECB + (q2 - 4096)]  = ldin(decb, q2 - 4096,   flag);
    } else {
        // gumbel table: g = -log(-log(u+1e-10)+1e-10); 253952 elems, 8/thread, 124 blocks
        int t = (blk - 659) * 256 + tid;
#pragma unroll
        for (int j = 0; j < 8; j++) {
            int e = t * 8 + j;
            float u = ldin(gum, e, flag);
            gws[e] = -logf(-logf(u + 1e-10f) + 1e-10f);
        }
    }
}

// ---------------- K1: embed MLP + s1 + qk via MFMA (blocks 0..255)
//                    + concurrent packing for later kernels (blocks 256..648) ----------------
__global__ __launch_bounds__(256) void k_embed(const void* emb, const float* W_,
                                               const void* h1w, const void* h2w, const void* h2b,
                                               const void* hew, const void* heb, const void* decw,
                                               const void* vw,
                                               u16* aeb, float* qkws, float* s1ws) {
    int flag = detect_flag(emb);
    float* W = (float*)W_;
    int blk = blockIdx.x;
    int tid = threadIdx.x;
    if (blk >= 256) {
        if (blk < 384) {
            // DECWT pack, vectorized 8/thread
            int t = (blk - 256) * 256 + tid;
            int lane = t & 63, tile = t >> 6;
            int nt = tile & 31, kt = tile >> 5;
            int n = nt * 16 + (lane & 15);
            int k0 = kt * 32 + ((lane >> 4) << 3);
            u16 tmp[8];
#pragma unroll
            for (int j = 0; j < 8; j++) tmp[j] = f2bbits(ldin(decw, n * 512 + k0 + j, flag));
            *reinterpret_cast<int4*>((u16*)(W + W_DECWT) + t * 8) = *reinterpret_cast<int4*>(tmp);
        } else if (blk < 388) {
            // W1EP pack (edge cols 256..262 of h1w, pad to 8), vectorized
            int t = (blk - 384) * 256 + tid;   // < 1024
            int lane = t & 63, nt = t >> 6;
            int n = nt * 16 + (lane & 15);
            int k0 = (lane >> 4) << 3;
            u16 tmp[8];
#pragma unroll
            for (int j = 0; j < 8; j++) {
                int k = k0 + j;
                tmp[j] = (k < 7) ? f2bbits(ldin(h1w, n * 263 + 256 + k, flag)) : (u16)0;
            }
            *reinterpret_cast<int4*>((u16*)(W + W_W1EP) + t * 8) = *reinterpret_cast<int4*>(tmp);
        } else if (blk < 392) {
            // VWP pack (K=10 real, pad to 32), vectorized
            int t = (blk - 388) * 256 + tid;   // < 1024
            int lane = t & 63, nt = t >> 6;
            int n = nt * 16 + (lane & 15);
            int k0 = (lane >> 4) << 3;
            u16 tmp[8];
#pragma unroll
            for (int j = 0; j < 8; j++) {
                int k = k0 + j;
                tmp[j] = (k < 10) ? f2bbits(ldin(vw, n * 10 + k, flag)) : (u16)0;
            }
            *reinterpret_cast<int4*>((u16*)(W + W_VWP) + t * 8) = *reinterpret_cast<int4*>(tmp);
        } else if (blk < 648) {
            // HE2P: E'[c][n] = sum_d hew[n][d]*h2w[d][c]; 16 lanes per entry
            int q = (blk - 392) * 16 + (tid >> 4);
            int l = tid & 15;
            int jj = q & 7, lane = (q >> 3) & 63, kt = q >> 9;
            int n = lane & 15;
            int c = kt * 32 + ((lane >> 4) << 3) + jj;
            float v = 0.f;
            if (n < 2) {
#pragma unroll
                for (int dd = 0; dd < 16; dd++) {
                    int d = l + 16 * dd;
                    v += ldin(hew, n * 256 + d, flag) * ldin(h2w, d * 256 + c, flag);
                }
            }
            v += __shfl_xor(v, 1, 64); v += __shfl_xor(v, 2, 64);
            v += __shfl_xor(v, 4, 64); v += __shfl_xor(v, 8, 64);
            if (l == 0) ((u16*)(W + W_HE2P))[q] = f2bbits(v);
        } else {
            // CB: cb[i] = (he_row_i . h2b) + heb[i]
            if (tid < 32) {
                int i = tid >> 4, l = tid & 15;
                float v = 0.f;
#pragma unroll
                for (int dd = 0; dd < 16; dd++) {
                    int d = l + 16 * dd;
                    v += ldin(hew, i * 256 + d, flag) * ldin(h2b, d, flag);
                }
                v += __shfl_xor(v, 1, 64); v += __shfl_xor(v, 2, 64);
                v += __shfl_xor(v, 4, 64); v += __shfl_xor(v, 8, 64);
                if (l == 0) W[W_CB + i] = v + ldin(heb, i, flag);
            }
        }
        return;
    }
    // ---- embed path (blocks 0..255, 16 rows each) ----
    int r0 = blk * 16;
    __shared__ float embL[16][12];
    __shared__ u16 hB[16][136];
    __shared__ u16 aeB[16][264];
    for (int idx = tid; idx < 16 * 11; idx += 256) {
        int s = idx / 11, t = idx % 11;
        embL[s][t] = ldin(emb, (r0 + s) * 11 + t, flag);
    }
    __syncthreads();
    for (int idx = tid; idx < 16 * 128; idx += 256) {
        int s = idx >> 7, jo = idx & 127;
        float v = W[W_E1B + jo];
#pragma unroll
        for (int t = 0; t < 5; t++) v += W[W_E1W + jo * 5 + t] * embL[s][4 + t];
        hB[s][jo] = f2bbits(v > 0.f ? v : 0.01f * v);
    }
    __syncthreads();
    int wv = tid >> 6, ln = tid & 63;
    int lr = ln & 15, quad = ln >> 4;
    {
        const bf16x8* Bp = (const bf16x8*)(W + W_E2P);
        f32x4 acc[4];
#pragma unroll
        for (int nt = 0; nt < 4; nt++) acc[nt] = (f32x4){0.f, 0.f, 0.f, 0.f};
#pragma unroll
        for (int kt = 0; kt < 4; kt++) {
            bf16x8 af = *(const bf16x8*)&hB[lr][kt * 32 + (quad << 3)];
#pragma unroll
            for (int nt = 0; nt < 4; nt++) {
                bf16x8 bfr = Bp[(kt * 16 + (wv * 4 + nt)) * 64 + ln];
                acc[nt] = __builtin_amdgcn_mfma_f32_16x16x32_bf16(af, bfr, acc[nt], 0, 0, 0);
            }
        }
#pragma unroll
        for (int nt = 0; nt < 4; nt++) {
            int d = wv * 64 + nt * 16 + lr;
            float bias = W[W_E2B + d];
#pragma unroll
            for (int reg = 0; reg < 4; reg++) {
                int m = quad * 4 + reg;
                float v = acc[nt][reg] + bias;
                v = v > 0.f ? v : 0.01f * v;
                u16 bits = f2bbits(v);
                aeB[m][d] = bits;
                aeb[(r0 + m) * 256 + d] = bits;
            }
        }
    }
    __syncthreads();
    {
        const bf16x8* Bs = (const bf16x8*)(W + W_S1P);
        f32x4 sac[4];
#pragma unroll
        for (int nt = 0; nt < 4; nt++) sac[nt] = (f32x4){0.f, 0.f, 0.f, 0.f};
#pragma unroll
        for (int kt = 0; kt < 8; kt++) {
            bf16x8 af = *(const bf16x8*)&aeB[lr][kt * 32 + (quad << 3)];
#pragma unroll
            for (int nt = 0; nt < 4; nt++) {
                bf16x8 bs = Bs[(kt * 16 + (wv * 4 + nt)) * 64 + ln];
                sac[nt] = __builtin_amdgcn_mfma_f32_16x16x32_bf16(af, bs, sac[nt], 0, 0, 0);
            }
        }
#pragma unroll
        for (int nt = 0; nt < 4; nt++) {
            int d = wv * 64 + nt * 16 + lr;
            float bias = W[W_H1B + d];
#pragma unroll
            for (int reg = 0; reg < 4; reg++) {
                int m = quad * 4 + reg;
                s1ws[(r0 + m) * 256 + d] = sac[nt][reg] + bias;
            }
        }
        if (wv == 0) {
            const bf16x8* Bm = (const bf16x8*)(W + W_QKM);
            f32x4 qk = (f32x4){0.f, 0.f, 0.f, 0.f};
#pragma unroll
            for (int kt = 0; kt < 8; kt++) {
                bf16x8 af = *(const bf16x8*)&aeB[lr][kt * 32 + (quad << 3)];
                qk = __builtin_amdgcn_mfma_f32_16x16x32_bf16(af, Bm[kt * 64 + ln], qk, 0, 0, 0);
            }
            if (lr < 10) {
#pragma unroll
                for (int reg = 0; reg < 4; reg++) {
                    int m = quad * 4 + reg;
                    qkws[(r0 + m) * 10 + lr] = qk[reg];
                }
            }
        }
    }
}

// ---------------- K2: fused edges + hard MLP + gumbel + attention + V-MFMA + entropy ----------------
// Latency-bound. R6-proven prefetch + 3-barrier restructure:
//   head: prefetch || direct-load edge features (no embB LDS roundtrip)
//   barrier A; stage A (MFMA, writes a1); barrier B;
//   wave0: stage B' (all 8 kt, in-wave pjL) + stage C; barrier C; stage D.
__global__ __launch_bounds__(256) void k_fused(const void* emb, const float* gws,
                                               const float* s1ws, const float* qkws, const float* W,
                                               u16* xb, float* entws, void* out) {
    int flag = detect_flag(emb);
    int r = blockIdx.x;
    int b = r >> 5, i = r & 31;
    __shared__ float seL[32][10];
    __shared__ __align__(16) u16 eA[32][40];   // rows 80 B; each row written by ONE thread
    __shared__ u16 a1[32][264];
    __shared__ float pjL[32][2];
    __shared__ float cL[32];
    __shared__ float qkL[10];
    int tid = threadIdx.x;
    int wv = tid >> 6, ln = tid & 63;
    int lr = ln & 15, quad = ln >> 4;
    // ---- early prefetch (hides global latency under the edge phase) ----
    float s1pre[4], vbpre[4];
#pragma unroll
    for (int nt = 0; nt < 4; nt++) {
        int d = (wv * 4 + nt) * 16 + lr;
        s1pre[nt] = s1ws[r * 256 + d];
        vbpre[nt] = W[W_VB + d];
    }
    float2 g01 = make_float2(0.f, 0.f);
    float cb0 = 0.f, cb1 = 0.f;
    if (wv == 0) {
        cb0 = W[W_CB + 0];
        cb1 = W[W_CB + 1];
        if (ln < NJ) g01 = *reinterpret_cast<const float2*>(&gws[(r * NJ + ln) * 2]);
    }
    if (tid >= 64 && tid < 74) qkL[tid - 64] = qkws[r * 10 + (tid - 64)];
    // ---- edge features: direct global loads, one full eA row per thread ----
    if (tid < NJ) {
        int jp = tid;
        int j = jp + (jp >= i ? 1 : 0);
        int ri = (b * 32 + i) * 11, rj = (b * 32 + j) * 11;
        float pix = ldin(emb, ri + 0, flag), piy = ldin(emb, ri + 1, flag);
        float hix = ldin(emb, ri + 2, flag), hiy = ldin(emb, ri + 3, flag);
        float pjx = ldin(emb, rj + 0, flag), pjy = ldin(emb, rj + 1, flag);
        float hjx = ldin(emb, rj + 2, flag), hjy = ldin(emb, rj + 3, flag);
        float ajx = ldin(emb, rj + 7, flag), ajy = ldin(emb, rj + 8, flag);
        float gjx = ldin(emb, rj + 9, flag), gjy = ldin(emb, rj + 10, flag);
        float hn2 = hix * hix + hiy * hiy;
        float csh, snh;
        if (hn2 == 0.f) { csh = 1.f; snh = 0.f; }
        else { float invh = rsqrtf(hn2); csh = hix * invh; snh = hiy * invh; }
        float dx = pjx - pix, dy = pjy - piy;
        float d2 = dx * dx + dy * dy;
        float dist, csd, snd;
        if (d2 == 0.f) { dist = 0.f; csd = 1.f; snd = 0.f; }
        else { float invd = rsqrtf(d2); dist = d2 * invd; csd = dx * invd; snd = dy * invd; }
        float gx = gjx - pix, gy = gjy - piy;
        float g2 = gx * gx + gy * gy;
        float gdist, csg, sng;
        if (g2 == 0.f) { gdist = 0.f; csg = 1.f; sng = 0.f; }
        else { float invg = rsqrtf(g2); gdist = g2 * invg; csg = gx * invg; sng = gy * invg; }
        float f[10];
        f[0] = dist * (1.f / 12.f);
        f[1] = csd * csh + snd * snh;      // cos(theta_d - theta_h)
        f[2] = snd * csh - csd * snh;      // sin(theta_d - theta_h)
        f[3] = hjx; f[4] = hjy; f[5] = ajx; f[6] = ajy;
        f[7] = gdist;
        f[8] = csg * csh + sng * snh;
        f[9] = sng * csh - csg * snh;
        u16 rowb[40];
#pragma unroll
        for (int t = 0; t < 10; t++) { seL[jp][t] = f[t]; rowb[t] = f2bbits(f[t]); }
#pragma unroll
        for (int t = 10; t < 40; t++) rowb[t] = 0;
#pragma unroll
        for (int q = 0; q < 5; q++)
            reinterpret_cast<int4*>(&eA[jp][0])[q] = reinterpret_cast<int4*>(rowb)[q];
        stout(out, OUT2 + r * NJ + jp, dist, flag);
    } else if (tid == NJ) {
        int4 z = make_int4(0, 0, 0, 0);
#pragma unroll
        for (int q = 0; q < 5; q++) reinterpret_cast<int4*>(&eA[31][0])[q] = z;
    }
    __syncthreads();   // barrier A: eA, seL, qkL ready
    // A-fragments shared by stage A (W1e: zeros for k>=7) and stage V (vw: zeros for k>=10)
    bf16x8 af0 = *(const bf16x8*)&eA[lr][quad << 3];
    bf16x8 af1 = *(const bf16x8*)&eA[16 + lr][quad << 3];
    f32x4 vacc[2][4];
    {
        const bf16x8* Bp = (const bf16x8*)(W + W_W1EP);
        const bf16x8* Bv = (const bf16x8*)(W + W_VWP);
#pragma unroll
        for (int nt = 0; nt < 4; nt++) {
            int gnt = wv * 4 + nt;
            int d = gnt * 16 + lr;
            float s1v = s1pre[nt];
            f32x4 acc0 = (f32x4){s1v, s1v, s1v, s1v};
            f32x4 acc1 = acc0;
            bf16x8 bb = Bp[gnt * 64 + ln];
            acc0 = __builtin_amdgcn_mfma_f32_16x16x32_bf16(af0, bb, acc0, 0, 0, 0);
            acc1 = __builtin_amdgcn_mfma_f32_16x16x32_bf16(af1, bb, acc1, 0, 0, 0);
#pragma unroll
            for (int reg = 0; reg < 4; reg++) {
                a1[(quad << 2) + reg][d]      = f2bbits(fmaxf(acc0[reg], 0.f));
                a1[16 + (quad << 2) + reg][d] = f2bbits(fmaxf(acc1[reg], 0.f));
            }
            // V = edge @ vw^T (bias applied in epilogue)
            bf16x8 bv = Bv[gnt * 64 + ln];
            f32x4 z = (f32x4){0.f, 0.f, 0.f, 0.f};
            vacc[0][nt] = __builtin_amdgcn_mfma_f32_16x16x32_bf16(af0, bv, z, 0, 0, 0);
            vacc[1][nt] = __builtin_amdgcn_mfma_f32_16x16x32_bf16(af1, bv, z, 0, 0, 0);
        }
    }
    __syncthreads();   // barrier B: a1 ready
    // ---- wave 0: stage B' (all 8 kt; pjL written and read in-wave) + stage C ----
    if (wv == 0) {
        const bf16x8* Ep = (const bf16x8*)(W + W_HE2P);
        f32x4 l0 = (f32x4){0.f, 0.f, 0.f, 0.f};
        f32x4 l1 = (f32x4){0.f, 0.f, 0.f, 0.f};
#pragma unroll
        for (int kt = 0; kt < 8; kt++) {
            bf16x8 a0  = *(const bf16x8*)&a1[lr][kt * 32 + (quad << 3)];
            bf16x8 a1f = *(const bf16x8*)&a1[16 + lr][kt * 32 + (quad << 3)];
            bf16x8 bb = Ep[kt * 64 + ln];
            l0 = __builtin_amdgcn_mfma_f32_16x16x32_bf16(a0, bb, l0, 0, 0, 0);
            l1 = __builtin_amdgcn_mfma_f32_16x16x32_bf16(a1f, bb, l1, 0, 0, 0);
        }
        if (lr < 2) {
#pragma unroll
            for (int reg = 0; reg < 4; reg++) {
                pjL[(quad << 2) + reg][lr]      = l0[reg];
                pjL[16 + (quad << 2) + reg][lr] = l1[reg];
            }
        }
        if (ln == 31) cL[31] = 0.f;   // padded j-row for V epilogue
        float hwv = 0.f;
        if (ln < NJ) {
            float p0 = pjL[ln][0] + cb0;
            float p1 = pjL[ln][1] + cb1;
            float dl = ((p1 + g01.y) - (p0 + g01.x)) * 2.0f;  // / tau (=0.5)
            hwv = 1.f / (1.f + __expf(-dl));
            stout(out, OUT1 + r * NJ + ln, p1, flag);
            stout(out, OUT4 + r * NJ + ln, hwv, flag);
        }
        float sc = -1e30f;
        if (ln < NJ) {
            float p = 0.f;
#pragma unroll
            for (int t = 0; t < 10; t++) p += qkL[t] * seL[ln][t];
            sc = p * (1.f / 16.f);
        }
        // 32-lane reductions (NJ=31 lives in lanes 0..31; upper half irrelevant)
        float m = sc;
#pragma unroll
        for (int s = 16; s >= 1; s >>= 1) m = fmaxf(m, __shfl_xor(m, s, 64));
        float e = (ln < NJ) ? __expf(sc - m) : 0.f;
        float sum = e;
#pragma unroll
        for (int s = 16; s >= 1; s >>= 1) sum += __shfl_xor(sum, s, 64);
        float sw = e / sum;
        float cmb = sw * hwv;
        if (ln < NJ) {
            cL[ln] = cmb;
            stout(out, OUT5 + r * NJ + ln, cmb, flag);
        }
        float csum = cmb;
#pragma unroll
        for (int s = 16; s >= 1; s >>= 1) csum += __shfl_xor(csum, s, 64);
        float cwn = cmb / (csum + 1e-6f);
        float et = (ln < NJ) ? -cwn * __logf(cwn + 1e-6f) : 0.f;
#pragma unroll
        for (int s = 16; s >= 1; s >>= 1) et += __shfl_xor(et, s, 64);
        if (ln == 0) entws[r] = et;
    }
    __syncthreads();   // barrier C: cL ready
    // stage D: x[d] = sum_j relu(V[j][d] + vb[d]) * combined_j  (from V-MFMA accumulators)
    {
        float cj[2][4];
#pragma unroll
        for (int mt = 0; mt < 2; mt++)
#pragma unroll
            for (int reg = 0; reg < 4; reg++) cj[mt][reg] = cL[mt * 16 + (quad << 2) + reg];
#pragma unroll
        for (int nt = 0; nt < 4; nt++) {
            int d = (wv * 4 + nt) * 16 + lr;
            float xp = 0.f;
#pragma unroll
            for (int mt = 0; mt < 2; mt++)
#pragma unroll
                for (int reg = 0; reg < 4; reg++)
                    xp += fmaxf(vacc[mt][nt][reg] + vbpre[nt], 0.f) * cj[mt][reg];
            xp += __shfl_xor(xp, 16, 64);
            xp += __shfl_xor(xp, 32, 64);
            if (quad == 0) xb[r * 256 + d] = f2bbits(xp);
        }
    }
}

// ---------------- K3: decoder via MFMA (16-row blocks, 1024 blocks) + entropy epilogue ----------------
__global__ __launch_bounds__(256) void k_dec(const void* emb, const u16* aeb, const u16* xb,
                                             const float* W, const float* entws, void* out) {
    int flag = detect_flag(emb);
    int r0 = (blockIdx.x >> 2) * 16;
    int nq = blockIdx.x & 3;
    __shared__ u16 finB[16][520];
    int tid = threadIdx.x;
    for (int idx = tid; idx < 16 * 64; idx += 256) {
        int s = idx >> 6, c8 = idx & 63;
        int4 v;
        if (c8 < 32) v = *reinterpret_cast<const int4*>(aeb + (r0 + s) * 256 + c8 * 8);
        else         v = *reinterpret_cast<const int4*>(xb  + (r0 + s) * 256 + (c8 - 32) * 8);
        *reinterpret_cast<int4*>(&finB[s][c8 * 8]) = v;
    }
    __syncthreads();
    int wv = tid >> 6, ln = tid & 63;
    int lr = ln & 15, quad = ln >> 4;
    const bf16x8* Bp = (const bf16x8*)(W + W_DECWT);
    f32x4 acc[2];
    acc[0] = (f32x4){0.f, 0.f, 0.f, 0.f};
    acc[1] = (f32x4){0.f, 0.f, 0.f, 0.f};
#pragma unroll
    for (int kt = 0; kt < 16; kt++) {
        bf16x8 af = *(const bf16x8*)&finB[lr][kt * 32 + (quad << 3)];
#pragma unroll
        for (int nt = 0; nt < 2; nt++) {
            int gnt = nq * 8 + wv * 2 + nt;
            bf16x8 bfr = Bp[(kt * 32 + gnt) * 64 + ln];
            acc[nt] = __builtin_amdgcn_mfma_f32_16x16x32_bf16(af, bfr, acc[nt], 0, 0, 0);
        }
    }
#pragma unroll
    for (int nt = 0; nt < 2; nt++) {
        int d = (nq * 8 + wv * 2 + nt) * 16 + lr;
        float bias = W[W_DECB + d];
#pragma unroll
        for (int reg = 0; reg < 4; reg++) {
            int m = quad * 4 + reg;
            stout(out, OUT0 + (r0 + m) * 512 + d, acc[nt][reg] + bias, flag);
        }
    }
    // entropy mean epilogue on block 0 (entws is complete before this kernel starts)
    if (blockIdx.x == 0) {
        __shared__ float red[4];
        float s = 0.f;
        for (int i2 = tid; i2 < R_TOT; i2 += 256) s += entws[i2];
#pragma unroll
        for (int m = 32; m >= 1; m >>= 1) s += __shfl_xor(s, m, 64);
        if ((tid & 63) == 0) red[tid >> 6] = s;
        __syncthreads();
        if (tid == 0) {
            float t = red[0] + red[1] + red[2] + red[3];
            stout(out, OUT3, t / (float)R_TOT, flag);
        }
    }
}

// ---------------- launch ----------------
extern "C" void kernel_launch(void* const* d_in, const int* in_sizes, int n_in,
                              void* d_out, int out_size, void* d_ws, size_t ws_size,
                              hipStream_t stream) {
    const void* emb  = d_in[0];
    const void* gum  = d_in[1];
    const void* e1w  = d_in[2];
    const void* e1b  = d_in[3];
    const void* e2w  = d_in[4];
    const void* e2b  = d_in[5];
    const void* h1w  = d_in[6];
    const void* h1b  = d_in[7];
    const void* h2w  = d_in[8];
    const void* h2b  = d_in[9];
    const void* hew  = d_in[10];
    const void* heb  = d_in[11];
    const void* qw   = d_in[12];
    const void* kw   = d_in[13];
    const void* vw   = d_in[14];
    const void* vb   = d_in[15];
    const void* decw = d_in[16];
    const void* decb = d_in[17];

    float* wsf = (float*)d_ws;
    u16*   aeb  = (u16*)(wsf + OFF_AE);
    float* qkws = wsf + OFF_QK;
    float* s1ws = wsf + OFF_S1;
    float* entw = wsf + OFF_ENT;
    u16*   xb   = (u16*)(wsf + OFF_X);
    float* W    = wsf + OFF_W;
    float* gws  = wsf + OFF_G;

    hipLaunchKernelGGL(k_prep, dim3(783), dim3(256), 0, stream,
                       emb, gum, e1w, e1b, e2w, e2b, h1w, h1b, qw, kw, vw, vb, decb, W, gws);
    hipLaunchKernelGGL(k_embed, dim3(649), dim3(256), 0, stream,
                       emb, W, h1w, h2w, h2b, hew, heb, decw, vw, aeb, qkws, s1ws);
    hipLaunchKernelGGL(k_fused, dim3(4096), dim3(256), 0, stream,
                       emb, gws, s1ws, qkws, W, xb, entw, d_out);
    hipLaunchKernelGGL(k_dec, dim3(1024), dim3(256), 0, stream, emb, aeb, xb, W, entw, d_out);
}

// Round 9
// 140.951 us; speedup vs baseline: 1.0755x; 1.0295x over previous
//
#include <hip/hip_runtime.h>
#include <hip/hip_bf16.h>
#include <math.h>

typedef __hip_bfloat16 bf16;
typedef short bf16x8 __attribute__((ext_vector_type(8)));
typedef float f32x4 __attribute__((ext_vector_type(4)));
typedef unsigned short u16;

#define R_TOT 4096   // B*N
#define NJ 31

// ---- workspace layout (float element offsets) ----
#define OFF_AE   0          // ae as bf16 u16 (4096*256)
#define OFF_QK   1048576    // qk: 4096*10 floats
#define OFF_S1   2097152    // s1: 4096*256 floats
#define OFF_ENT  4542464    // 4096 floats
#define OFF_X    4546560    // x as bf16 u16 (4096*256)
#define OFF_W    5595136    // canonical weights base
#define OFF_G    6100992    // gumbel table: 4096*31*2 floats
// relative to W:
#define W_E1W   0
#define W_E1B   640
#define W_E2P   768        // e2 B-pack: 32768 bf16
#define W_E2B   33536
#define W_H1B   101120
#define W_VWP   101376     // vw B-pack: 8192 bf16
#define W_W1EP  167684     // W1e B-pack: 8192 bf16
#define W_HE2P  171780     // E = he@hm2 B-pack: 4096 bf16
#define W_CB    173828     // cb0, cb1
#define W_S1P   200452     // s1 B-pack: 65536 bf16
#define W_VW    235780
#define W_VB    238340
#define W_DECWT 238596     // dec B-pack: 262144 bf16
#define W_DECB  500740
#define W_QKM   501252     // M = qw^T@kw B-pack: 4096 bf16

// ---- output element offsets ----
#define OUT0 0
#define OUT1 2097152
#define OUT2 2224128
#define OUT3 2351104
#define OUT4 2351105
#define OUT5 2478081

__device__ __forceinline__ float b2f(bf16 x) { return __bfloat162float(x); }
__device__ __forceinline__ float ldin(const void* p, int i, int flag) {
    return flag ? b2f(((const bf16*)p)[i]) : ((const float*)p)[i];
}
__device__ __forceinline__ void stout(void* p, int i, float v, int flag) {
    if (flag) ((bf16*)p)[i] = __float2bfloat16(v);
    else      ((float*)p)[i] = v;
}
__device__ __forceinline__ u16 f2bbits(float v) {
    bf16 h = __float2bfloat16(v);
    return *(u16*)&h;
}
// per-wave inline dtype detect: P(misclassify) = 0.4^64 ~ 0
__device__ __forceinline__ int detect_flag(const void* emb) {
    float x = ((const float*)emb)[threadIdx.x & 63];
    int sane = (x == x) && (fabsf(x) < 1e20f);
    unsigned long long m = __ballot(sane);
    return (__popcll(m) == 64) ? 0 : 1;  // 0=fp32, 1=bf16
}

// ---------------- K0: prep what k_embed needs + gumbel table (783 blocks) ----------------
__global__ __launch_bounds__(256) void k_prep(
        const void* emb, const void* gum,
        const void* e1w, const void* e1b, const void* e2w, const void* e2b,
        const void* h1w, const void* h1b, const void* qw,  const void* kw,
        const void* vw,  const void* vb,  const void* decb,
        float* W, float* gws) {
    int flag = detect_flag(emb);
    int blk = blockIdx.x;
    int tid = threadIdx.x;
    if (blk < 384) {
        int p; const void* src; int ldm, Wdst;
        if (blk < 128) { p = blk * 256 + tid;         src = e2w; ldm = 128; Wdst = W_E2P; }
        else           { p = (blk - 128) * 256 + tid; src = h1w; ldm = 263; Wdst = W_S1P; }
        int jj   = p & 7;
        int lane = (p >> 3) & 63;
        int tile = p >> 9;
        int nt = tile & 15, kt = tile >> 4;
        int n = nt * 16 + (lane & 15);
        int k = kt * 32 + ((lane >> 4) << 3) + jj;
        ((u16*)(W + Wdst))[p] = f2bbits(ldin(src, n * ldm + k, flag));
    } else if (blk < 640) {
        // qkm: M[c][n] = sum_d qw[d*256+c]*kw[d*10+n]; 16 lanes per entry
        int p = (blk - 384) * 16 + (tid >> 4);
        int l = tid & 15;
        int jj = p & 7, lane = (p >> 3) & 63, kt = p >> 9;
        int k = kt * 32 + ((lane >> 4) << 3) + jj;
        int n = lane & 15;
        float v = 0.f;
        if (n < 10) {
#pragma unroll
            for (int dd = 0; dd < 16; dd++) {
                int d = l + 16 * dd;
                v += ldin(qw, d * 256 + k, flag) * ldin(kw, d * 10 + n, flag);
            }
        }
        v += __shfl_xor(v, 1, 64); v += __shfl_xor(v, 2, 64);
        v += __shfl_xor(v, 4, 64); v += __shfl_xor(v, 8, 64);
        if (l == 0) ((u16*)(W + W_QKM))[p] = f2bbits(v);
    } else if (blk < 659) {
        int q2 = (blk - 640) * 256 + tid;
        if      (q2 < 640)   W[W_E1W  + q2]           = ldin(e1w,  q2,          flag);
        else if (q2 < 768)   W[W_E1B  + (q2 - 640)]   = ldin(e1b,  q2 - 640,    flag);
        else if (q2 < 1024)  W[W_E2B  + (q2 - 768)]   = ldin(e2b,  q2 - 768,    flag);
        else if (q2 < 1280)  W[W_H1B  + (q2 - 1024)]  = ldin(h1b,  q2 - 1024,   flag);
        else if (q2 < 3840)  W[W_VW   + (q2 - 1280)]  = ldin(vw,   q2 - 1280,   flag);
        else if (q2 < 4096)  W[W_VB   + (q2 - 3840)]  = ldin(vb,   q2 - 3840,   flag);
        else if (q2 < 4608)  W[W_DECB + (q2 - 4096)]  = ldin(decb, q2 - 4096,   flag);
    } else {
        // gumbel table: g = -log(-log(u+1e-10)+1e-10); 253952 elems, 8/thread, 124 blocks
        int t = (blk - 659) * 256 + tid;
#pragma unroll
        for (int j = 0; j < 8; j++) {
            int e = t * 8 + j;
            float u = ldin(gum, e, flag);
            gws[e] = -logf(-logf(u + 1e-10f) + 1e-10f);
        }
    }
}

// ---------------- K1: embed MLP + s1 + qk via MFMA (blocks 0..255)
//                    + concurrent packing for later kernels (blocks 256..648) ----------------
__global__ __launch_bounds__(256) void k_embed(const void* emb, const float* W_,
                                               const void* h1w, const void* h2w, const void* h2b,
                                               const void* hew, const void* heb, const void* decw,
                                               const void* vw,
                                               u16* aeb, float* qkws, float* s1ws) {
    int flag = detect_flag(emb);
    float* W = (float*)W_;
    int blk = blockIdx.x;
    int tid = threadIdx.x;
    if (blk >= 256) {
        if (blk < 384) {
            // DECWT pack, vectorized 8/thread
            int t = (blk - 256) * 256 + tid;
            int lane = t & 63, tile = t >> 6;
            int nt = tile & 31, kt = tile >> 5;
            int n = nt * 16 + (lane & 15);
            int k0 = kt * 32 + ((lane >> 4) << 3);
            u16 tmp[8];
#pragma unroll
            for (int j = 0; j < 8; j++) tmp[j] = f2bbits(ldin(decw, n * 512 + k0 + j, flag));
            *reinterpret_cast<int4*>((u16*)(W + W_DECWT) + t * 8) = *reinterpret_cast<int4*>(tmp);
        } else if (blk < 388) {
            // W1EP pack (edge cols 256..262 of h1w, pad to 8), vectorized
            int t = (blk - 384) * 256 + tid;   // < 1024
            int lane = t & 63, nt = t >> 6;
            int n = nt * 16 + (lane & 15);
            int k0 = (lane >> 4) << 3;
            u16 tmp[8];
#pragma unroll
            for (int j = 0; j < 8; j++) {
                int k = k0 + j;
                tmp[j] = (k < 7) ? f2bbits(ldin(h1w, n * 263 + 256 + k, flag)) : (u16)0;
            }
            *reinterpret_cast<int4*>((u16*)(W + W_W1EP) + t * 8) = *reinterpret_cast<int4*>(tmp);
        } else if (blk < 392) {
            // VWP pack (K=10 real, pad to 32), vectorized
            int t = (blk - 388) * 256 + tid;   // < 1024
            int lane = t & 63, nt = t >> 6;
            int n = nt * 16 + (lane & 15);
            int k0 = (lane >> 4) << 3;
            u16 tmp[8];
#pragma unroll
            for (int j = 0; j < 8; j++) {
                int k = k0 + j;
                tmp[j] = (k < 10) ? f2bbits(ldin(vw, n * 10 + k, flag)) : (u16)0;
            }
            *reinterpret_cast<int4*>((u16*)(W + W_VWP) + t * 8) = *reinterpret_cast<int4*>(tmp);
        } else if (blk < 648) {
            // HE2P: E'[c][n] = sum_d hew[n][d]*h2w[d][c]; 16 lanes per entry
            int q = (blk - 392) * 16 + (tid >> 4);
            int l = tid & 15;
            int jj = q & 7, lane = (q >> 3) & 63, kt = q >> 9;
            int n = lane & 15;
            int c = kt * 32 + ((lane >> 4) << 3) + jj;
            float v = 0.f;
            if (n < 2) {
#pragma unroll
                for (int dd = 0; dd < 16; dd++) {
                    int d = l + 16 * dd;
                    v += ldin(hew, n * 256 + d, flag) * ldin(h2w, d * 256 + c, flag);
                }
            }
            v += __shfl_xor(v, 1, 64); v += __shfl_xor(v, 2, 64);
            v += __shfl_xor(v, 4, 64); v += __shfl_xor(v, 8, 64);
            if (l == 0) ((u16*)(W + W_HE2P))[q] = f2bbits(v);
        } else {
            // CB: cb[i] = (he_row_i . h2b) + heb[i]
            if (tid < 32) {
                int i = tid >> 4, l = tid & 15;
                float v = 0.f;
#pragma unroll
                for (int dd = 0; dd < 16; dd++) {
                    int d = l + 16 * dd;
                    v += ldin(hew, i * 256 + d, flag) * ldin(h2b, d, flag);
                }
                v += __shfl_xor(v, 1, 64); v += __shfl_xor(v, 2, 64);
                v += __shfl_xor(v, 4, 64); v += __shfl_xor(v, 8, 64);
                if (l == 0) W[W_CB + i] = v + ldin(heb, i, flag);
            }
        }
        return;
    }
    // ---- embed path (blocks 0..255, 16 rows each) ----
    int r0 = blk * 16;
    __shared__ float embL[16][12];
    __shared__ u16 hB[16][136];
    __shared__ u16 aeB[16][264];
    for (int idx = tid; idx < 16 * 11; idx += 256) {
        int s = idx / 11, t = idx % 11;
        embL[s][t] = ldin(emb, (r0 + s) * 11 + t, flag);
    }
    __syncthreads();
    for (int idx = tid; idx < 16 * 128; idx += 256) {
        int s = idx >> 7, jo = idx & 127;
        float v = W[W_E1B + jo];
#pragma unroll
        for (int t = 0; t < 5; t++) v += W[W_E1W + jo * 5 + t] * embL[s][4 + t];
        hB[s][jo] = f2bbits(v > 0.f ? v : 0.01f * v);
    }
    __syncthreads();
    int wv = tid >> 6, ln = tid & 63;
    int lr = ln & 15, quad = ln >> 4;
    {
        const bf16x8* Bp = (const bf16x8*)(W + W_E2P);
        f32x4 acc[4];
#pragma unroll
        for (int nt = 0; nt < 4; nt++) acc[nt] = (f32x4){0.f, 0.f, 0.f, 0.f};
#pragma unroll
        for (int kt = 0; kt < 4; kt++) {
            bf16x8 af = *(const bf16x8*)&hB[lr][kt * 32 + (quad << 3)];
#pragma unroll
            for (int nt = 0; nt < 4; nt++) {
                bf16x8 bfr = Bp[(kt * 16 + (wv * 4 + nt)) * 64 + ln];
                acc[nt] = __builtin_amdgcn_mfma_f32_16x16x32_bf16(af, bfr, acc[nt], 0, 0, 0);
            }
        }
#pragma unroll
        for (int nt = 0; nt < 4; nt++) {
            int d = wv * 64 + nt * 16 + lr;
            float bias = W[W_E2B + d];
#pragma unroll
            for (int reg = 0; reg < 4; reg++) {
                int m = quad * 4 + reg;
                float v = acc[nt][reg] + bias;
                v = v > 0.f ? v : 0.01f * v;
                u16 bits = f2bbits(v);
                aeB[m][d] = bits;
                aeb[(r0 + m) * 256 + d] = bits;
            }
        }
    }
    __syncthreads();
    {
        const bf16x8* Bs = (const bf16x8*)(W + W_S1P);
        f32x4 sac[4];
#pragma unroll
        for (int nt = 0; nt < 4; nt++) sac[nt] = (f32x4){0.f, 0.f, 0.f, 0.f};
#pragma unroll
        for (int kt = 0; kt < 8; kt++) {
            bf16x8 af = *(const bf16x8*)&aeB[lr][kt * 32 + (quad << 3)];
#pragma unroll
            for (int nt = 0; nt < 4; nt++) {
                bf16x8 bs = Bs[(kt * 16 + (wv * 4 + nt)) * 64 + ln];
                sac[nt] = __builtin_amdgcn_mfma_f32_16x16x32_bf16(af, bs, sac[nt], 0, 0, 0);
            }
        }
#pragma unroll
        for (int nt = 0; nt < 4; nt++) {
            int d = wv * 64 + nt * 16 + lr;
            float bias = W[W_H1B + d];
#pragma unroll
            for (int reg = 0; reg < 4; reg++) {
                int m = quad * 4 + reg;
                s1ws[(r0 + m) * 256 + d] = sac[nt][reg] + bias;
            }
        }
        if (wv == 0) {
            const bf16x8* Bm = (const bf16x8*)(W + W_QKM);
            f32x4 qk = (f32x4){0.f, 0.f, 0.f, 0.f};
#pragma unroll
            for (int kt = 0; kt < 8; kt++) {
                bf16x8 af = *(const bf16x8*)&aeB[lr][kt * 32 + (quad << 3)];
                qk = __builtin_amdgcn_mfma_f32_16x16x32_bf16(af, Bm[kt * 64 + ln], qk, 0, 0, 0);
            }
            if (lr < 10) {
#pragma unroll
                for (int reg = 0; reg < 4; reg++) {
                    int m = quad * 4 + reg;
                    qkws[(r0 + m) * 10 + lr] = qk[reg];
                }
            }
        }
    }
}

// ---------------- K2: fused edges + hard MLP + gumbel + attention + V-MFMA + entropy ----------------
// Latency-bound. R8-proven 3-barrier skeleton + R9 split:
//   barrier B -> wave0: logits MFMA + sigmoid -> hwvL ; wave1: attn softmax -> swL (parallel)
//   barrier C -> all waves stage D (cj = swL*hwvL); wave0 entropy tail runs post-barrier,
//   concurrent with other waves' stage D (nothing in-block depends on it).
__global__ __launch_bounds__(256) void k_fused(const void* emb, const float* gws,
                                               const float* s1ws, const float* qkws, const float* W,
                                               u16* xb, float* entws, void* out) {
    int flag = detect_flag(emb);
    int r = blockIdx.x;
    int b = r >> 5, i = r & 31;
    __shared__ float seL[32][10];
    __shared__ __align__(16) u16 eA[32][40];   // rows 80 B; each row written by ONE thread
    __shared__ u16 a1[32][264];
    __shared__ float pjL[32][2];
    __shared__ float hwvL[32];
    __shared__ float swL[32];
    __shared__ float qkL[10];
    int tid = threadIdx.x;
    int wv = tid >> 6, ln = tid & 63;
    int lr = ln & 15, quad = ln >> 4;
    // ---- early prefetch (hides global latency under the edge phase) ----
    float s1pre[4], vbpre[4];
#pragma unroll
    for (int nt = 0; nt < 4; nt++) {
        int d = (wv * 4 + nt) * 16 + lr;
        s1pre[nt] = s1ws[r * 256 + d];
        vbpre[nt] = W[W_VB + d];
    }
    float2 g01 = make_float2(0.f, 0.f);
    float cb0 = 0.f, cb1 = 0.f;
    if (wv == 0) {
        cb0 = W[W_CB + 0];
        cb1 = W[W_CB + 1];
        if (ln < NJ) g01 = *reinterpret_cast<const float2*>(&gws[(r * NJ + ln) * 2]);
    }
    if (tid >= 64 && tid < 74) qkL[tid - 64] = qkws[r * 10 + (tid - 64)];
    // ---- edge features: direct global loads, one full eA row per thread ----
    if (tid < NJ) {
        int jp = tid;
        int j = jp + (jp >= i ? 1 : 0);
        int ri = (b * 32 + i) * 11, rj = (b * 32 + j) * 11;
        float pix = ldin(emb, ri + 0, flag), piy = ldin(emb, ri + 1, flag);
        float hix = ldin(emb, ri + 2, flag), hiy = ldin(emb, ri + 3, flag);
        float pjx = ldin(emb, rj + 0, flag), pjy = ldin(emb, rj + 1, flag);
        float hjx = ldin(emb, rj + 2, flag), hjy = ldin(emb, rj + 3, flag);
        float ajx = ldin(emb, rj + 7, flag), ajy = ldin(emb, rj + 8, flag);
        float gjx = ldin(emb, rj + 9, flag), gjy = ldin(emb, rj + 10, flag);
        float hn2 = hix * hix + hiy * hiy;
        float csh, snh;
        if (hn2 == 0.f) { csh = 1.f; snh = 0.f; }
        else { float invh = rsqrtf(hn2); csh = hix * invh; snh = hiy * invh; }
        float dx = pjx - pix, dy = pjy - piy;
        float d2 = dx * dx + dy * dy;
        float dist, csd, snd;
        if (d2 == 0.f) { dist = 0.f; csd = 1.f; snd = 0.f; }
        else { float invd = rsqrtf(d2); dist = d2 * invd; csd = dx * invd; snd = dy * invd; }
        float gx = gjx - pix, gy = gjy - piy;
        float g2 = gx * gx + gy * gy;
        float gdist, csg, sng;
        if (g2 == 0.f) { gdist = 0.f; csg = 1.f; sng = 0.f; }
        else { float invg = rsqrtf(g2); gdist = g2 * invg; csg = gx * invg; sng = gy * invg; }
        float f[10];
        f[0] = dist * (1.f / 12.f);
        f[1] = csd * csh + snd * snh;      // cos(theta_d - theta_h)
        f[2] = snd * csh - csd * snh;      // sin(theta_d - theta_h)
        f[3] = hjx; f[4] = hjy; f[5] = ajx; f[6] = ajy;
        f[7] = gdist;
        f[8] = csg * csh + sng * snh;
        f[9] = sng * csh - csg * snh;
        u16 rowb[40];
#pragma unroll
        for (int t = 0; t < 10; t++) { seL[jp][t] = f[t]; rowb[t] = f2bbits(f[t]); }
#pragma unroll
        for (int t = 10; t < 40; t++) rowb[t] = 0;
#pragma unroll
        for (int q = 0; q < 5; q++)
            reinterpret_cast<int4*>(&eA[jp][0])[q] = reinterpret_cast<int4*>(rowb)[q];
        stout(out, OUT2 + r * NJ + jp, dist, flag);
    } else if (tid == NJ) {
        int4 z = make_int4(0, 0, 0, 0);
#pragma unroll
        for (int q = 0; q < 5; q++) reinterpret_cast<int4*>(&eA[31][0])[q] = z;
    }
    __syncthreads();   // barrier A: eA, seL, qkL ready
    // A-fragments shared by stage A (W1e: zeros for k>=7) and stage V (vw: zeros for k>=10)
    bf16x8 af0 = *(const bf16x8*)&eA[lr][quad << 3];
    bf16x8 af1 = *(const bf16x8*)&eA[16 + lr][quad << 3];
    f32x4 vacc[2][4];
    {
        const bf16x8* Bp = (const bf16x8*)(W + W_W1EP);
        const bf16x8* Bv = (const bf16x8*)(W + W_VWP);
#pragma unroll
        for (int nt = 0; nt < 4; nt++) {
            int gnt = wv * 4 + nt;
            int d = gnt * 16 + lr;
            float s1v = s1pre[nt];
            f32x4 acc0 = (f32x4){s1v, s1v, s1v, s1v};
            f32x4 acc1 = acc0;
            bf16x8 bb = Bp[gnt * 64 + ln];
            acc0 = __builtin_amdgcn_mfma_f32_16x16x32_bf16(af0, bb, acc0, 0, 0, 0);
            acc1 = __builtin_amdgcn_mfma_f32_16x16x32_bf16(af1, bb, acc1, 0, 0, 0);
#pragma unroll
            for (int reg = 0; reg < 4; reg++) {
                a1[(quad << 2) + reg][d]      = f2bbits(fmaxf(acc0[reg], 0.f));
                a1[16 + (quad << 2) + reg][d] = f2bbits(fmaxf(acc1[reg], 0.f));
            }
            // V = edge @ vw^T (bias applied in epilogue)
            bf16x8 bv = Bv[gnt * 64 + ln];
            f32x4 z = (f32x4){0.f, 0.f, 0.f, 0.f};
            vacc[0][nt] = __builtin_amdgcn_mfma_f32_16x16x32_bf16(af0, bv, z, 0, 0, 0);
            vacc[1][nt] = __builtin_amdgcn_mfma_f32_16x16x32_bf16(af1, bv, z, 0, 0, 0);
        }
    }
    __syncthreads();   // barrier B: a1 ready
    float hwv = 0.f;   // wave 0 keeps its lane's hwv for the entropy tail
    if (wv == 0) {
        // ---- logits: all 8 kt in-wave; pjL written and read within wave 0 ----
        const bf16x8* Ep = (const bf16x8*)(W + W_HE2P);
        f32x4 l0 = (f32x4){0.f, 0.f, 0.f, 0.f};
        f32x4 l1 = (f32x4){0.f, 0.f, 0.f, 0.f};
#pragma unroll
        for (int kt = 0; kt < 8; kt++) {
            bf16x8 a0  = *(const bf16x8*)&a1[lr][kt * 32 + (quad << 3)];
            bf16x8 a1f = *(const bf16x8*)&a1[16 + lr][kt * 32 + (quad << 3)];
            bf16x8 bb = Ep[kt * 64 + ln];
            l0 = __builtin_amdgcn_mfma_f32_16x16x32_bf16(a0, bb, l0, 0, 0, 0);
            l1 = __builtin_amdgcn_mfma_f32_16x16x32_bf16(a1f, bb, l1, 0, 0, 0);
        }
        if (lr < 2) {
#pragma unroll
            for (int reg = 0; reg < 4; reg++) {
                pjL[(quad << 2) + reg][lr]      = l0[reg];
                pjL[16 + (quad << 2) + reg][lr] = l1[reg];
            }
        }
        if (ln < NJ) {
            float p0 = pjL[ln][0] + cb0;
            float p1 = pjL[ln][1] + cb1;
            float dl = ((p1 + g01.y) - (p0 + g01.x)) * 2.0f;  // / tau (=0.5)
            hwv = 1.f / (1.f + __expf(-dl));
            stout(out, OUT1 + r * NJ + ln, p1, flag);
            stout(out, OUT4 + r * NJ + ln, hwv, flag);
        }
        if (ln < 32) hwvL[ln] = hwv;      // 0 for ln=31 pad
    } else if (wv == 1) {
        // ---- attention softmax (independent of a1; inputs ready since barrier A) ----
        float sc = -1e30f;
        if (ln < NJ) {
            float p = 0.f;
#pragma unroll
            for (int t = 0; t < 10; t++) p += qkL[t] * seL[ln][t];
            sc = p * (1.f / 16.f);
        }
        float m = sc;
#pragma unroll
        for (int s = 16; s >= 1; s >>= 1) m = fmaxf(m, __shfl_xor(m, s, 64));
        float e = (ln < NJ) ? __expf(sc - m) : 0.f;
        float sum = e;
#pragma unroll
        for (int s = 16; s >= 1; s >>= 1) sum += __shfl_xor(sum, s, 64);
        float sw = e / sum;
        if (ln < 32) swL[ln] = sw;        // 0 for ln=31 pad (e=0)
    }
    __syncthreads();   // barrier C: hwvL, swL ready
    // stage D: x[d] = sum_j relu(V[j][d] + vb[d]) * (swL[j]*hwvL[j])
    {
        float cj[2][4];
#pragma unroll
        for (int mt = 0; mt < 2; mt++)
#pragma unroll
            for (int reg = 0; reg < 4; reg++) {
                int j = mt * 16 + (quad << 2) + reg;
                cj[mt][reg] = swL[j] * hwvL[j];
            }
#pragma unroll
        for (int nt = 0; nt < 4; nt++) {
            int d = (wv * 4 + nt) * 16 + lr;
            float xp = 0.f;
#pragma unroll
            for (int mt = 0; mt < 2; mt++)
#pragma unroll
                for (int reg = 0; reg < 4; reg++)
                    xp += fmaxf(vacc[mt][nt][reg] + vbpre[nt], 0.f) * cj[mt][reg];
            xp += __shfl_xor(xp, 16, 64);
            xp += __shfl_xor(xp, 32, 64);
            if (quad == 0) xb[r * 256 + d] = f2bbits(xp);
        }
    }
    // ---- wave 0 entropy tail: concurrent with other waves' stage D; no in-block consumer ----
    if (wv == 0) {
        float cmb = (ln < NJ) ? swL[ln] * hwv : 0.f;
        if (ln < NJ) stout(out, OUT5 + r * NJ + ln, cmb, flag);
        float csum = cmb;
#pragma unroll
        for (int s = 16; s >= 1; s >>= 1) csum += __shfl_xor(csum, s, 64);
        float cwn = cmb / (csum + 1e-6f);
        float et = (ln < NJ) ? -cwn * __logf(cwn + 1e-6f) : 0.f;
#pragma unroll
        for (int s = 16; s >= 1; s >>= 1) et += __shfl_xor(et, s, 64);
        if (ln == 0) entws[r] = et;
    }
}

// ---------------- K3: decoder via MFMA (16-row blocks, 1024 blocks) + entropy epilogue ----------------
__global__ __launch_bounds__(256) void k_dec(const void* emb, const u16* aeb, const u16* xb,
                                             const float* W, const float* entws, void* out) {
    int flag = detect_flag(emb);
    int r0 = (blockIdx.x >> 2) * 16;
    int nq = blockIdx.x & 3;
    __shared__ u16 finB[16][520];
    int tid = threadIdx.x;
    for (int idx = tid; idx < 16 * 64; idx += 256) {
        int s = idx >> 6, c8 = idx & 63;
        int4 v;
        if (c8 < 32) v = *reinterpret_cast<const int4*>(aeb + (r0 + s) * 256 + c8 * 8);
        else         v = *reinterpret_cast<const int4*>(xb  + (r0 + s) * 256 + (c8 - 32) * 8);
        *reinterpret_cast<int4*>(&finB[s][c8 * 8]) = v;
    }
    __syncthreads();
    int wv = tid >> 6, ln = tid & 63;
    int lr = ln & 15, quad = ln >> 4;
    const bf16x8* Bp = (const bf16x8*)(W + W_DECWT);
    f32x4 acc[2];
    acc[0] = (f32x4){0.f, 0.f, 0.f, 0.f};
    acc[1] = (f32x4){0.f, 0.f, 0.f, 0.f};
#pragma unroll
    for (int kt = 0; kt < 16; kt++) {
        bf16x8 af = *(const bf16x8*)&finB[lr][kt * 32 + (quad << 3)];
#pragma unroll
        for (int nt = 0; nt < 2; nt++) {
            int gnt = nq * 8 + wv * 2 + nt;
            bf16x8 bfr = Bp[(kt * 32 + gnt) * 64 + ln];
            acc[nt] = __builtin_amdgcn_mfma_f32_16x16x32_bf16(af, bfr, acc[nt], 0, 0, 0);
        }
    }
#pragma unroll
    for (int nt = 0; nt < 2; nt++) {
        int d = (nq * 8 + wv * 2 + nt) * 16 + lr;
        float bias = W[W_DECB + d];
#pragma unroll
        for (int reg = 0; reg < 4; reg++) {
            int m = quad * 4 + reg;
            stout(out, OUT0 + (r0 + m) * 512 + d, acc[nt][reg] + bias, flag);
        }
    }
    // entropy mean epilogue on block 0 (entws is complete before this kernel starts)
    if (blockIdx.x == 0) {
        __shared__ float red[4];
        float s = 0.f;
        for (int i2 = tid; i2 < R_TOT; i2 += 256) s += entws[i2];
#pragma unroll
        for (int m = 32; m >= 1; m >>= 1) s += __shfl_xor(s, m, 64);
        if ((tid & 63) == 0) red[tid >> 6] = s;
        __syncthreads();
        if (tid == 0) {
            float t = red[0] + red[1] + red[2] + red[3];
            stout(out, OUT3, t / (float)R_TOT, flag);
        }
    }
}

// ---------------- launch ----------------
extern "C" void kernel_launch(void* const* d_in, const int* in_sizes, int n_in,
                              void* d_out, int out_size, void* d_ws, size_t ws_size,
                              hipStream_t stream) {
    const void* emb  = d_in[0];
    const void* gum  = d_in[1];
    const void* e1w  = d_in[2];
    const void* e1b  = d_in[3];
    const void* e2w  = d_in[4];
    const void* e2b  = d_in[5];
    const void* h1w  = d_in[6];
    const void* h1b  = d_in[7];
    const void* h2w  = d_in[8];
    const void* h2b  = d_in[9];
    const void* hew  = d_in[10];
    const void* heb  = d_in[11];
    const void* qw   = d_in[12];
    const void* kw   = d_in[13];
    const void* vw   = d_in[14];
    const void* vb   = d_in[15];
    const void* decw = d_in[16];
    const void* decb = d_in[17];

    float* wsf = (float*)d_ws;
    u16*   aeb  = (u16*)(wsf + OFF_AE);
    float* qkws = wsf + OFF_QK;
    float* s1ws = wsf + OFF_S1;
    float* entw = wsf + OFF_ENT;
    u16*   xb   = (u16*)(wsf + OFF_X);
    float* W    = wsf + OFF_W;
    float* gws  = wsf + OFF_G;

    hipLaunchKernelGGL(k_prep, dim3(783), dim3(256), 0, stream,
                       emb, gum, e1w, e1b, e2w, e2b, h1w, h1b, qw, kw, vw, vb, decb, W, gws);
    hipLaunchKernelGGL(k_embed, dim3(649), dim3(256), 0, stream,
                       emb, W, h1w, h2w, h2b, hew, heb, decw, vw, aeb, qkws, s1ws);
    hipLaunchKernelGGL(k_fused, dim3(4096), dim3(256), 0, stream,
                       emb, gws, s1ws, qkws, W, xb, entw, d_out);
    hipLaunchKernelGGL(k_dec, dim3(1024), dim3(256), 0, stream, emb, aeb, xb, W, entw, d_out);
}